// Round 2
// 329.692 us; speedup vs baseline: 1.1103x; 1.1103x over previous
//
#include <hip/hip_runtime.h>
#include <stdint.h>
#include <stddef.h>

// MHA forward: B=4 T=2048 H=16 Dk=64 D=1024, fp32 in/out, fp16 MFMA internally.
// cvt weights(+acts) -> fused QKV GEMM -> transposed-score flash attention -> output GEMM.
// R2: GEMMs double-buffered (prefetch-before-compute, 1 barrier/K-iter) with
// XOR seg-swizzle (linear LDS dest for global_load_lds, swizzled global SOURCE,
// swizzled READ) to kill the 16-way bank conflict on fragment reads.
// (R1 compile fix: no arrays of LDS pointers — scalar offset arithmetic instead.)

typedef __attribute__((ext_vector_type(4))) float f32x4;
typedef __attribute__((ext_vector_type(8))) _Float16 f16x8;
typedef __attribute__((ext_vector_type(4))) _Float16 f16x4;

#define DEV __device__ __forceinline__

constexpr int BATCH = 4, SEQ = 2048, NH = 16, DK = 64, DM = 1024;
constexpr int MROWS = BATCH * SEQ; // 8192
// log2-domain softmax: fold 1/sqrt(64) * log2(e) into Q projection
constexpr float QSCALE = 0.125f * 1.4426950408889634f;

DEV void async16(const void* g, void* l) {
  __builtin_amdgcn_global_load_lds(
      (const __attribute__((address_space(1))) unsigned int*)g,
      (__attribute__((address_space(3))) unsigned int*)l, 16, 0, 0);
}

// ---------------- fp32 -> fp16 converters ----------------
__global__ void cvt_w_kernel(const float* __restrict__ w0, const float* __restrict__ w1,
                             const float* __restrict__ w2, const float* __restrict__ w3,
                             _Float16* __restrict__ o0, _Float16* __restrict__ o1,
                             _Float16* __restrict__ o2, _Float16* __restrict__ o3) {
  size_t i = (size_t)blockIdx.x * blockDim.x + threadIdx.x;
  const float* ws[4] = {w0, w1, w2, w3};
  _Float16* os[4] = {o0, o1, o2, o3};
#pragma unroll
  for (int m = 0; m < 4; m++) {
    f32x4 x = *(const f32x4*)(ws[m] + i * 4);
    f16x4 h;
#pragma unroll
    for (int j = 0; j < 4; j++) h[j] = (_Float16)x[j];
    *(f16x4*)(os[m] + i * 4) = h;
  }
}

__global__ void cvt_act_kernel(const float* __restrict__ a0, const float* __restrict__ a1,
                               const float* __restrict__ a2, _Float16* __restrict__ o0,
                               _Float16* __restrict__ o1, _Float16* __restrict__ o2) {
  size_t i = (size_t)blockIdx.x * blockDim.x + threadIdx.x;
  const float* as[3] = {a0, a1, a2};
  _Float16* os[3] = {o0, o1, o2};
#pragma unroll
  for (int m = 0; m < 3; m++) {
    f32x4 x = *(const f32x4*)(as[m] + i * 4);
    f16x4 h;
#pragma unroll
    for (int j = 0; j < 4; j++) h[j] = (_Float16)x[j];
    *(f16x4*)(os[m] + i * 4) = h;
  }
}

struct QKVPtrs {
  const float* a32[3];
  const _Float16* a16[3];
  const _Float16* w[3];
  const float* bias[3];
  _Float16* out[3];
};

// Stage a 128x64 fp16 tile into LDS (linear [128][64] layout, 16B granules),
// with the global SOURCE segment XOR-swizzled so that LDS slot (row, s) holds
// global segment s ^ (row&7). Reader applies the same XOR -> 2-way (free)
// instead of 16-way bank conflict on ds_read_b128.
DEV void stage_g16(const _Float16* __restrict__ src, int k0, _Float16* dst, int tid) {
  const int wave = tid >> 6;
#pragma unroll
  for (int it = 0; it < 4; it++) {
    int idx = it * 256 + tid;
    int row = idx >> 3, seg = idx & 7;
    async16(src + (size_t)row * DM + k0 + ((seg ^ (row & 7)) << 3),
            (char*)dst + (size_t)(it * 256 + wave * 64) * 16);
  }
}

// fp32->fp16 convert-stage (small-workspace path): plain loads + swizzled ds_write.
DEV void stage_f32(const float* __restrict__ src, int k0, _Float16* dst, int tid) {
#pragma unroll
  for (int it = 0; it < 4; it++) {
    int idx = it * 256 + tid;
    int row = idx >> 3, seg = idx & 7;
    const float* g = src + (size_t)row * DM + k0 + seg * 8;
    f32x4 x0 = *(const f32x4*)g;
    f32x4 x1 = *(const f32x4*)(g + 4);
    f16x8 h;
#pragma unroll
    for (int j = 0; j < 4; j++) { h[j] = (_Float16)x0[j]; h[4 + j] = (_Float16)x1[j]; }
    *(f16x8*)&dst[row * 64 + ((seg ^ (row & 7)) << 3)] = h;
  }
}

// ---------------- fused QKV GEMM: C = A[M,K] * W[N,K]^T + bias ----------------
// grid (m=64, n=8, z=3): same-m blocks have linear ids congruent mod 8 -> same XCD L2.
// z=0: Q -> [B,H,T,64] (scaled by QSCALE); z=1: K -> [B,H,T,64]; z=2: V -> [B,H,64,T]
template <bool AH>
__global__ __launch_bounds__(256) void gemm_qkv_kernel(QKVPtrs P) {
  constexpr int K = DM;
  // [buf0: A|B][buf1: A|B], 16KB each tile -> 64KB total; epilogue reuses as Ct[128*144]
  __shared__ __align__(16) _Float16 smem[4 * 128 * 64];
  const int z = blockIdx.z;
  const _Float16* Bw = P.w[z];
  const int tid = threadIdx.x;
  const int wave = tid >> 6, lane = tid & 63;
  const int quad = lane >> 4, l16 = lane & 15;
  const int wm = wave >> 1, wn = wave & 1;
  const int m0 = blockIdx.x * 128, n0 = blockIdx.y * 128;
  const float scale = (z == 0) ? QSCALE : 1.0f;

  const _Float16* Bg = Bw + (size_t)n0 * K;
  const _Float16* Ag16 = AH ? P.a16[z] + (size_t)m0 * K : nullptr;
  const float* Ag32 = AH ? nullptr : P.a32[z] + (size_t)m0 * K;

  const f32x4 zero4 = {0.f, 0.f, 0.f, 0.f};
  f32x4 acc[4][4];
#pragma unroll
  for (int mt = 0; mt < 4; mt++)
#pragma unroll
    for (int nt = 0; nt < 4; nt++) acc[mt][nt] = zero4;

  float bv[4];
#pragma unroll
  for (int nt = 0; nt < 4; nt++) bv[nt] = P.bias[z][n0 + wn * 64 + nt * 16 + l16];

  // prologue: stage tile 0 into buf 0 (A at +0, B at +8192; buf1 at +16384)
  stage_g16(Bg, 0, smem + 8192, tid);
  if (AH) stage_g16(Ag16, 0, smem, tid);
  else    stage_f32(Ag32, 0, smem, tid);
  __syncthreads();

  for (int kt = 0; kt < K / 64; kt++) {
    const int boff = (kt & 1) ? 16384 : 0;
    const _Float16* Asc = smem + boff;
    const _Float16* Bsc = smem + 8192 + boff;
    if (kt + 1 < K / 64) {
      // prefetch next tile into the other buffer; latency hides under MFMA below
      const int k0 = (kt + 1) * 64;
      const int poff = boff ^ 16384;
      stage_g16(Bg, k0, smem + 8192 + poff, tid);
      if (AH) stage_g16(Ag16, k0, smem + poff, tid);
      else    stage_f32(Ag32, k0, smem + poff, tid);
    }
    __builtin_amdgcn_s_setprio(1);
#pragma unroll
    for (int ks = 0; ks < 2; ks++) {
      f16x8 af[4], bfr[4];
#pragma unroll
      for (int mt = 0; mt < 4; mt++) {
        int r = wm * 64 + mt * 16 + l16;
        af[mt] = *(const f16x8*)&Asc[r * 64 + (((ks * 4 + quad) ^ (r & 7)) << 3)];
      }
#pragma unroll
      for (int nt = 0; nt < 4; nt++) {
        int r = wn * 64 + nt * 16 + l16;
        bfr[nt] = *(const f16x8*)&Bsc[r * 64 + (((ks * 4 + quad) ^ (r & 7)) << 3)];
      }
#pragma unroll
      for (int mt = 0; mt < 4; mt++)
#pragma unroll
        for (int nt = 0; nt < 4; nt++)
          acc[mt][nt] = __builtin_amdgcn_mfma_f32_16x16x32_f16(af[mt], bfr[nt], acc[mt][nt], 0, 0, 0);
    }
    __builtin_amdgcn_s_setprio(0);
    __syncthreads(); // drains prefetch vmcnt + releases buffers
  }

  // epilogue via LDS (stride 144), coalesced global stores
  _Float16* Ct = smem;
  const int b = m0 >> 11, tbase = m0 & (SEQ - 1);
  if (z < 2) {
#pragma unroll
    for (int mt = 0; mt < 4; mt++)
#pragma unroll
      for (int nt = 0; nt < 4; nt++)
#pragma unroll
        for (int i = 0; i < 4; i++)
          Ct[(wm * 64 + mt * 16 + quad * 4 + i) * 144 + wn * 64 + nt * 16 + l16] =
              (_Float16)((acc[mt][nt][i] + bv[nt]) * scale);
  } else {
#pragma unroll
    for (int mt = 0; mt < 4; mt++)
#pragma unroll
      for (int nt = 0; nt < 4; nt++)
#pragma unroll
        for (int i = 0; i < 4; i++)
          Ct[(wn * 64 + nt * 16 + l16) * 144 + wm * 64 + mt * 16 + quad * 4 + i] =
              (_Float16)(acc[mt][nt][i] + bv[nt]);
  }
  __syncthreads();
  _Float16* out = P.out[z];
  if (z < 2) {
    const int row = tid >> 1, coff = (tid & 1) * 32;
#pragma unroll
    for (int hh = 0; hh < 2; hh++) {
      int h = (n0 >> 6) + hh;
      size_t gb = ((size_t)(b * NH + h) * SEQ + tbase) * 64 + (size_t)tid * 32;
#pragma unroll
      for (int k2 = 0; k2 < 4; k2++)
        *(f16x8*)&out[gb + k2 * 8] =
            *(const f16x8*)&Ct[row * 144 + hh * 64 + coff + k2 * 8];
    }
  } else {
#pragma unroll
    for (int k2 = 0; k2 < 8; k2++) {
      int c = k2 * 256 + tid;
      int n = c >> 4, s2 = c & 15;
      int h = (n0 + n) >> 6, d = (n0 + n) & (DK - 1);
      size_t gb = ((size_t)(b * NH + h) * DK + d) * SEQ + tbase + s2 * 8;
      *(f16x8*)&out[gb] = *(const f16x8*)&Ct[n * 144 + s2 * 8];
    }
  }
}

// ---------------- output GEMM: fp16 A, fp32 out [M, DM]; grid (m=64, n=8) ----------------
__global__ __launch_bounds__(256) void gemm_out_kernel(
    const _Float16* __restrict__ Ah, const _Float16* __restrict__ Bw,
    const float* __restrict__ bias, float* __restrict__ Cp) {
  constexpr int K = DM;
  __shared__ __align__(16) _Float16 smem[4 * 128 * 64];
  const int tid = threadIdx.x;
  const int wave = tid >> 6, lane = tid & 63;
  const int quad = lane >> 4, l16 = lane & 15;
  const int wm = wave >> 1, wn = wave & 1;
  const int m0 = blockIdx.x * 128, n0 = blockIdx.y * 128;

  const _Float16* Bg = Bw + (size_t)n0 * K;
  const _Float16* Ag = Ah + (size_t)m0 * K;

  const f32x4 zero4 = {0.f, 0.f, 0.f, 0.f};
  f32x4 acc[4][4];
#pragma unroll
  for (int mt = 0; mt < 4; mt++)
#pragma unroll
    for (int nt = 0; nt < 4; nt++) acc[mt][nt] = zero4;

  float bv[4];
#pragma unroll
  for (int nt = 0; nt < 4; nt++) bv[nt] = bias[n0 + wn * 64 + nt * 16 + l16];

  stage_g16(Bg, 0, smem + 8192, tid);
  stage_g16(Ag, 0, smem, tid);
  __syncthreads();

  for (int kt = 0; kt < K / 64; kt++) {
    const int boff = (kt & 1) ? 16384 : 0;
    const _Float16* Asc = smem + boff;
    const _Float16* Bsc = smem + 8192 + boff;
    if (kt + 1 < K / 64) {
      const int k0 = (kt + 1) * 64;
      const int poff = boff ^ 16384;
      stage_g16(Bg, k0, smem + 8192 + poff, tid);
      stage_g16(Ag, k0, smem + poff, tid);
    }
    __builtin_amdgcn_s_setprio(1);
#pragma unroll
    for (int ks = 0; ks < 2; ks++) {
      f16x8 af[4], bfr[4];
#pragma unroll
      for (int mt = 0; mt < 4; mt++) {
        int r = wm * 64 + mt * 16 + l16;
        af[mt] = *(const f16x8*)&Asc[r * 64 + (((ks * 4 + quad) ^ (r & 7)) << 3)];
      }
#pragma unroll
      for (int nt = 0; nt < 4; nt++) {
        int r = wn * 64 + nt * 16 + l16;
        bfr[nt] = *(const f16x8*)&Bsc[r * 64 + (((ks * 4 + quad) ^ (r & 7)) << 3)];
      }
#pragma unroll
      for (int mt = 0; mt < 4; mt++)
#pragma unroll
        for (int nt = 0; nt < 4; nt++)
          acc[mt][nt] = __builtin_amdgcn_mfma_f32_16x16x32_f16(af[mt], bfr[nt], acc[mt][nt], 0, 0, 0);
    }
    __builtin_amdgcn_s_setprio(0);
    __syncthreads();
  }
#pragma unroll
  for (int mt = 0; mt < 4; mt++)
#pragma unroll
    for (int nt = 0; nt < 4; nt++)
#pragma unroll
      for (int i = 0; i < 4; i++) {
        int m = m0 + wm * 64 + mt * 16 + quad * 4 + i;
        int n = n0 + wn * 64 + nt * 16 + l16;
        Cp[(size_t)m * DM + n] = acc[mt][nt][i] + bv[nt];
      }
}

// ---------------- transposed-score flash attention (causal) ----------------
// S^T = mfma(A=K, B=Q): lane owns q=l16 -> 2-shuffle row reductions; the S^T C-frag
// IS the A-frag of mfma_f32_16x16x16f16 for PV (k=quad*4+reg) -> no P LDS round-trip.
// Q,K: [B,H,T,64] fp16 (Q pre-scaled); V: [B,H,64,T] fp16; O: [B,T,H*64] fp16.
// Blocks paired {qt, 15-qt}: uniform 17 k-iters. LDS padded: Ks stride 72, Vs stride 136.
__global__ __launch_bounds__(256, 2) void attn_kernel(
    const _Float16* __restrict__ Q, const _Float16* __restrict__ Kt,
    const _Float16* __restrict__ V, _Float16* __restrict__ O) {
  __shared__ __align__(16) _Float16 Ks[128 * 72];
  __shared__ __align__(16) _Float16 Vs[64 * 136];
  const int tid = threadIdx.x;
  const int wave = tid >> 6, lane = tid & 63, quad = lane >> 4, l16 = lane & 15;
  const int bh = blockIdx.y;
  const size_t base = (size_t)bh * SEQ * DK; // same stride for K-layout and V-layout
  const int b = bh >> 4, h = bh & 15;
  const f32x4 zero4 = {0.f, 0.f, 0.f, 0.f};

  for (int p = 0; p < 2; p++) {
    const int qt = (p == 0) ? (int)blockIdx.x : 15 - (int)blockIdx.x;
    const int t0 = qt * 128;

    // Q-frags (B-operand): lane n=l16 -> q-row, k=d=quad*8+j
    f16x8 qf[2][2];
#pragma unroll
    for (int mt = 0; mt < 2; mt++)
#pragma unroll
      for (int ks = 0; ks < 2; ks++)
        qf[mt][ks] = *(const f16x8*)(Q + base + (size_t)(t0 + wave * 32 + mt * 16 + l16) * DK +
                                     ks * 32 + quad * 8);

    f32x4 oacc[2][4];
#pragma unroll
    for (int mt = 0; mt < 2; mt++)
#pragma unroll
      for (int nt = 0; nt < 4; nt++) oacc[mt][nt] = zero4;
    float mrow[2] = {-1e30f, -1e30f}, lrow[2] = {0.f, 0.f};

    for (int j = 0; j <= qt; j++) {
      // stage K [128 tk][64 d] -> Ks (stride 72), V [64 d][128 tk] -> Vs (stride 136)
#pragma unroll
      for (int it = 0; it < 4; it++) {
        int c = it * 256 + tid;
        int row = c >> 3, off = (c & 7) * 8;
        *(f16x8*)&Ks[row * 72 + off] =
            *(const f16x8*)(Kt + base + (size_t)(j * 128 + row) * 64 + off);
      }
#pragma unroll
      for (int it = 0; it < 4; it++) {
        int c = it * 256 + tid;
        int d = c >> 4, off = (c & 15) * 8;
        *(f16x8*)&Vs[d * 136 + off] =
            *(const f16x8*)(V + base + ((size_t)d << 11) + j * 128 + off);
      }
      __syncthreads();

      // S^T frags: rows tk=quad*4+i (within nt*16 block), cols q=l16 (within wave*32+mt*16)
      f32x4 s[2][8];
#pragma unroll
      for (int nt = 0; nt < 8; nt++) {
        f16x8 kf0 = *(const f16x8*)&Ks[(nt * 16 + l16) * 72 + quad * 8];
        f16x8 kf1 = *(const f16x8*)&Ks[(nt * 16 + l16) * 72 + 32 + quad * 8];
#pragma unroll
        for (int mt = 0; mt < 2; mt++) {
          f32x4 zz = zero4;
          zz = __builtin_amdgcn_mfma_f32_16x16x32_f16(kf0, qf[mt][0], zz, 0, 0, 0);
          zz = __builtin_amdgcn_mfma_f32_16x16x32_f16(kf1, qf[mt][1], zz, 0, 0, 0);
          s[mt][nt] = zz;
        }
      }
      if (j == qt) { // diagonal: mask tk_local > q_local
#pragma unroll
        for (int mt = 0; mt < 2; mt++) {
          int qloc = wave * 32 + mt * 16 + l16;
#pragma unroll
          for (int nt = 0; nt < 8; nt++)
#pragma unroll
            for (int i = 0; i < 4; i++)
              if (nt * 16 + quad * 4 + i > qloc) s[mt][nt][i] = -1e30f;
        }
      }
      // online softmax: lane owns q=l16; reduce own 32 vals + xor16/xor32 across quads
#pragma unroll
      for (int mt = 0; mt < 2; mt++) {
        float mx = mrow[mt];
#pragma unroll
        for (int nt = 0; nt < 8; nt++)
#pragma unroll
          for (int i = 0; i < 4; i++) mx = fmaxf(mx, s[mt][nt][i]);
        mx = fmaxf(mx, __shfl_xor(mx, 16));
        mx = fmaxf(mx, __shfl_xor(mx, 32));
        float alpha = __builtin_exp2f(mrow[mt] - mx);
        mrow[mt] = mx;
        float rs = 0.f;
#pragma unroll
        for (int nt = 0; nt < 8; nt++)
#pragma unroll
          for (int i = 0; i < 4; i++) {
            float pv = __builtin_exp2f(s[mt][nt][i] - mx);
            s[mt][nt][i] = pv;
            rs += pv;
          }
        rs += __shfl_xor(rs, 16);
        rs += __shfl_xor(rs, 32);
        lrow[mt] = lrow[mt] * alpha + rs;
        // broadcast alpha to O-row owners (rows q=quad*4+i)
#pragma unroll
        for (int i = 0; i < 4; i++) {
          float ab = __shfl(alpha, quad * 4 + i);
#pragma unroll
          for (int nt = 0; nt < 4; nt++) oacc[mt][nt][i] *= ab;
        }
      }
      // PV: A-frag = cvt(S^T frag) in regs; B-frag = Vs rows (d=l16), k=tk=quad*4+j
#pragma unroll
      for (int jj = 0; jj < 8; jj++) {
        f16x4 pf[2];
#pragma unroll
        for (int mt = 0; mt < 2; mt++) {
          f16x4 t;
#pragma unroll
          for (int i = 0; i < 4; i++) t[i] = (_Float16)s[mt][jj][i];
          pf[mt] = t;
        }
#pragma unroll
        for (int nt = 0; nt < 4; nt++) {
          f16x4 vb = *(const f16x4*)&Vs[(nt * 16 + l16) * 136 + jj * 16 + quad * 4];
#pragma unroll
          for (int mt = 0; mt < 2; mt++)
            oacc[mt][nt] = __builtin_amdgcn_mfma_f32_16x16x16f16(pf[mt], vb, oacc[mt][nt], 0, 0, 0);
        }
      }
      __syncthreads();
    }
    // epilogue: O rows q=quad*4+i, cols d=l16; fetch 1/l via shuffle
#pragma unroll
    for (int mt = 0; mt < 2; mt++) {
      float linv = 1.0f / lrow[mt];
#pragma unroll
      for (int i = 0; i < 4; i++) {
        float lb = __shfl(linv, quad * 4 + i);
        int t = t0 + wave * 32 + mt * 16 + quad * 4 + i;
#pragma unroll
        for (int nt = 0; nt < 4; nt++) {
          int d = nt * 16 + l16;
          O[((size_t)(b * SEQ + t) << 10) + h * 64 + d] = (_Float16)(oacc[mt][nt][i] * lb);
        }
      }
    }
  }
}

extern "C" void kernel_launch(void* const* d_in, const int* in_sizes, int n_in,
                              void* d_out, int out_size, void* d_ws, size_t ws_size,
                              hipStream_t stream) {
  const float* query = (const float*)d_in[0];
  const float* key_  = (const float*)d_in[1];
  const float* value = (const float*)d_in[2];
  const float* W_q = (const float*)d_in[4];
  const float* b_q = (const float*)d_in[5];
  const float* W_k = (const float*)d_in[6];
  const float* b_k = (const float*)d_in[7];
  const float* W_v = (const float*)d_in[8];
  const float* b_v = (const float*)d_in[9];
  const float* W_o = (const float*)d_in[10];
  const float* b_o = (const float*)d_in[11];

  constexpr size_t WEL = (size_t)DM * DM;    // 1M halves
  constexpr size_t MEL = (size_t)MROWS * DM; // 8M halves
  _Float16* ws = (_Float16*)d_ws;
  _Float16* wq = ws;
  _Float16* wk = wq + WEL;
  _Float16* wv = wk + WEL;
  _Float16* wo = wv + WEL;

  // big layout: [weights 8MB][qh kh vh 48MB][qb kb vb 48MB]; ab overlays qh (dead by attn)
  const bool big = ws_size >= (size_t)(4 * WEL + 6 * MEL) * sizeof(_Float16);

  QKVPtrs P;
  P.a32[0] = query; P.a32[1] = key_; P.a32[2] = value;
  P.w[0] = wq; P.w[1] = wk; P.w[2] = wv;
  P.bias[0] = b_q; P.bias[1] = b_k; P.bias[2] = b_v;

  cvt_w_kernel<<<dim3((unsigned)(WEL / 4 / 256)), 256, 0, stream>>>(
      W_q, W_k, W_v, W_o, wq, wk, wv, wo);

  _Float16 *qb, *kb, *vb, *ab;
  if (big) {
    _Float16* qh = wo + WEL;
    _Float16* kh = qh + MEL;
    _Float16* vh = kh + MEL;
    qb = vh + MEL; kb = qb + MEL; vb = kb + MEL;
    ab = qh; // reuse
    P.a16[0] = qh; P.a16[1] = kh; P.a16[2] = vh;
    P.out[0] = qb; P.out[1] = kb; P.out[2] = vb;
    cvt_act_kernel<<<dim3((unsigned)(MEL / 4 / 256)), 256, 0, stream>>>(
        query, key_, value, qh, kh, vh);
    gemm_qkv_kernel<true><<<dim3(MROWS / 128, DM / 128, 3), 256, 0, stream>>>(P);
  } else {
    qb = wo + WEL; kb = qb + MEL; vb = kb + MEL; ab = vb + MEL;
    P.a16[0] = P.a16[1] = P.a16[2] = nullptr;
    P.out[0] = qb; P.out[1] = kb; P.out[2] = vb;
    gemm_qkv_kernel<false><<<dim3(MROWS / 128, DM / 128, 3), 256, 0, stream>>>(P);
  }

  attn_kernel<<<dim3(8, BATCH * NH), 256, 0, stream>>>(qb, kb, vb, ab);

  gemm_out_kernel<<<dim3(MROWS / 128, DM / 128), 256, 0, stream>>>(ab, wo, b_o, (float*)d_out);
}